// Round 6
// baseline (678.666 us; speedup 1.0000x reference)
//
#include <hip/hip_runtime.h>

#define N_NODES 50000
#define N_EDGES 1600000
#define R_REL 8
#define G_GRAPHS 64
#define D_INF 128
#define HIDF 128
#define CLSF 10

#define S_SEG (N_NODES * R_REL)   // 400000 (dst, rel) segments
#define RZ 9                      // 8 relations + root slice
#define PCHUNK 16                 // pool stage-1 chunks per graph

#define XG 8                      // XCD groups for partitioned sort
#define NODES_PER_G (N_NODES / XG)      // 6250
#define SORT_BLKS_PER_G 256
#define SORT_GRID (XG * SORT_BLKS_PER_G)

typedef __attribute__((ext_vector_type(8))) short short8;
typedef __attribute__((ext_vector_type(4))) float floatx4;

typedef __attribute__((address_space(1))) const unsigned int guint;
typedef __attribute__((address_space(3))) unsigned int luint;
__device__ __forceinline__ void gload_lds16(const void* g, void* l) {
    // async global->LDS, 16 B/lane; LDS dest = wave-uniform base + lane*16
    __builtin_amdgcn_global_load_lds((guint*)g, (luint*)l, 16, 0, 0);
}

__device__ __forceinline__ unsigned short f2bf(float f) {
    unsigned int u = __float_as_uint(f);
    unsigned int r = (u + 0x7fffu + ((u >> 16) & 1u)) >> 16;   // RNE
    return (unsigned short)r;
}
// exact unpack of a packed bf16 pair (uint32) into two fp32
__device__ __forceinline__ float bflo(unsigned int u) { return __uint_as_float(u << 16); }
__device__ __forceinline__ float bfhi(unsigned int u) { return __uint_as_float(u & 0xffff0000u); }

__device__ __forceinline__ int ntload(const int* p) { return __builtin_nontemporal_load(p); }

// ---------------- pack (dst, rel) -> segment id, one vectorized pass ---------
__global__ __launch_bounds__(256) void seg_kernel(const int* __restrict__ dst,
                                                  const int* __restrict__ et,
                                                  int* __restrict__ seg) {
    int i4 = blockIdx.x * 256 + threadIdx.x;
    if (i4 * 4 >= N_EDGES) return;
    int4 d = ((const int4*)dst)[i4];
    int4 t = ((const int4*)et)[i4];
    int4 s;
    s.x = d.x * R_REL + t.x; s.y = d.y * R_REL + t.y;
    s.z = d.z * R_REL + t.z; s.w = d.w * R_REL + t.w;
    ((int4*)seg)[i4] = s;
}

// ---------------- count edges per (dst, rel) segment — XCD-partitioned --------
// 8 filter passes: all atomics land in one XCD's L2 (no cross-XCD line ping-pong).
__global__ __launch_bounds__(256) void count_kernel(const int* __restrict__ seg,
                                                    int* __restrict__ cnt) {
    int xg = blockIdx.x & (XG - 1);
    int inner = blockIdx.x >> 3;
    int lo = xg * NODES_PER_G * R_REL, hi = lo + NODES_PER_G * R_REL;
    for (int e = inner * 256 + threadIdx.x; e < N_EDGES; e += SORT_BLKS_PER_G * 256) {
        int sg = ntload(seg + e);
        if (sg >= lo && sg < hi) atomicAdd(&cnt[sg], 1);
    }
}

// ---------------- scan over segment counts ----------------
#define SCAN_BLK 256
#define SCAN_ELEMS 1024
#define NB_SCAN ((S_SEG + SCAN_ELEMS - 1) / SCAN_ELEMS)   // 391

__global__ __launch_bounds__(SCAN_BLK) void scan1_kernel(const int* __restrict__ cnt,
                                                         int* __restrict__ off,
                                                         int* __restrict__ bsum) {
    __shared__ int sd[SCAN_BLK];
    int t = threadIdx.x;
    int base = blockIdx.x * SCAN_ELEMS + t * 4;
    int v[4];
    int tsum = 0;
#pragma unroll
    for (int j = 0; j < 4; j++) {
        v[j] = (base + j < S_SEG) ? cnt[base + j] : 0;
        tsum += v[j];
    }
    sd[t] = tsum;
    __syncthreads();
    for (int d = 1; d < SCAN_BLK; d <<= 1) {
        int x = (t >= d) ? sd[t - d] : 0;
        __syncthreads();
        sd[t] += x;
        __syncthreads();
    }
    int incl = sd[t];
    int run = incl - tsum;
#pragma unroll
    for (int j = 0; j < 4; j++) {
        if (base + j < S_SEG) off[base + j] = run;
        run += v[j];
    }
    if (t == SCAN_BLK - 1) bsum[blockIdx.x] = incl;
}

// fused: scan of block sums (redundant per block, 391 values in LDS)
// + absolute off + cursor init. Replaces scan2 + absoff + memcpy(cursor).
__global__ __launch_bounds__(512) void absoff2_kernel(int* __restrict__ off,
                                                      const int* __restrict__ bsum,
                                                      int* __restrict__ cursor) {
    __shared__ int sd[512];
    int t = threadIdx.x;
    int v = (t < NB_SCAN) ? bsum[t] : 0;
    sd[t] = v;
    __syncthreads();
    for (int d = 1; d < 512; d <<= 1) {
        int x = (t >= d) ? sd[t - d] : 0;
        __syncthreads();
        sd[t] += x;
        __syncthreads();
    }
    int pre = (blockIdx.x == 0) ? 0 : sd[blockIdx.x - 1];
    int base = blockIdx.x * SCAN_ELEMS + t * 2;
#pragma unroll
    for (int j = 0; j < 2; j++) {
        int i = base + j;
        if (i < S_SEG) {
            int o = off[i] + pre;
            off[i] = o;
            cursor[i] = o;
        }
    }
}

// ---------------- bin edges — XCD-partitioned; 2B src record -----------------
__global__ __launch_bounds__(256) void bin_kernel(const int* __restrict__ seg,
                                                  const int* __restrict__ src,
                                                  int* __restrict__ cursor,
                                                  unsigned short* __restrict__ esrc) {
    int xg = blockIdx.x & (XG - 1);
    int inner = blockIdx.x >> 3;
    int lo = xg * NODES_PER_G * R_REL, hi = lo + NODES_PER_G * R_REL;
    for (int e = inner * 256 + threadIdx.x; e < N_EDGES; e += SORT_BLKS_PER_G * 256) {
        int sg = ntload(seg + e);
        if (sg >= lo && sg < hi) {
            int pos = atomicAdd(&cursor[sg], 1);    // absolute position
            esrc[pos] = (unsigned short)ntload(src + e);
        }
    }
}

// ---------------- convert x fp32 -> bf16 compact [N,128] ----------------
__global__ void convx_kernel(const float* __restrict__ x, unsigned short* __restrict__ xb) {
    int idx = blockIdx.x * blockDim.x + threadIdx.x;
    if (idx < N_NODES * D_INF) xb[idx] = f2bf(x[idx]);
}

// ---------------- build bf16 weights wz[9][128][128]: [r][col][k] ----------
__global__ __launch_bounds__(256) void convw9_kernel(const float* __restrict__ W,
                                                     const float* __restrict__ root,
                                                     unsigned short* __restrict__ wz) {
    __shared__ float t[16][17];
    int r = blockIdx.z;
    int k0 = blockIdx.x * 16, c0 = blockIdx.y * 16;
    int tx = threadIdx.x & 15, ty = threadIdx.x >> 4;
    const float* srcp = (r < 8) ? (W + (size_t)r * 128 * 128) : root;
    t[ty][tx] = srcp[(size_t)(k0 + ty) * 128 + c0 + tx];
    __syncthreads();
    wz[(size_t)r * 16384 + (size_t)(c0 + ty) * 128 + k0 + tx] = f2bf(t[tx][ty]);
}

// ---------------- fused layer: gather-mean into LDS A-tile + MFMA + relu -----
// One block per 16 nodes (3125 blocks). Phase 1: 16 independent 16-lane groups
// each walk their node's 8 (dst,rel) segments (agg_mean inner loop) and write
// the bf16 mean rows into LDS A[8][4][16][32]. Phase 2: transform9's per-r
// B-staging + MFMA over K=1152; root slice (r=8) reads hsrc fragments straight
// from global (L2-hot). m[] is never materialized.
__global__ __launch_bounds__(256) void fused_layer(
    const unsigned short* __restrict__ hsrc,   // [N,128] bf16
    const unsigned short* __restrict__ esrc,   // src sorted by (dst,rel), 2B
    const int* __restrict__ off,               // [S_SEG] absolute starts
    const unsigned short* __restrict__ wz,     // [9][128][128] bf16 [r][col][k]
    const float* __restrict__ bias,
    unsigned short* __restrict__ hout)         // [N,128] bf16
{
    __shared__ __align__(16) unsigned short A8[8][4][16][32];  // 32 KB mean rows
    __shared__ __align__(16) unsigned short B4[4][128][32];    // 32 KB W_r slice

    const int tx = threadIdx.x;
    const int wave = tx >> 6, lane = tx & 63;
    const int quad = lane >> 4, lq = lane & 15;
    const int srow = lane >> 2, sch = lane & 3;
    const int n0 = blockIdx.x * 16;            // 50000 % 16 == 0: no tail
    const int grp = tx >> 4;                   // 0..15 -> node n0+grp
    const int l = tx & 15;                     // lane covers channels l*8..l*8+7

    // ---- phase 1: gather means for this tile's 128 segments ----
    const int node = n0 + grp;
#pragma unroll 1
    for (int r = 0; r < R_REL; r++) {
        int sg = node * R_REL + r;
        int beg = off[sg];
        int end = (sg + 1 < S_SEG) ? off[sg + 1] : N_EDGES;
        float w = 1.0f / (float)max(end - beg, 1);
        float a0 = 0.f, a1 = 0.f, a2 = 0.f, a3 = 0.f;
        float a4 = 0.f, a5 = 0.f, a6 = 0.f, a7 = 0.f;
        int e = beg;
        for (; e + 4 <= end; e += 4) {
            int s0 = esrc[e], s1 = esrc[e + 1], s2 = esrc[e + 2], s3 = esrc[e + 3];
            uint4 v0 = *(const uint4*)(hsrc + (size_t)s0 * HIDF + l * 8);
            uint4 v1 = *(const uint4*)(hsrc + (size_t)s1 * HIDF + l * 8);
            uint4 v2 = *(const uint4*)(hsrc + (size_t)s2 * HIDF + l * 8);
            uint4 v3 = *(const uint4*)(hsrc + (size_t)s3 * HIDF + l * 8);
            a0 += bflo(v0.x) + bflo(v1.x) + bflo(v2.x) + bflo(v3.x);
            a1 += bfhi(v0.x) + bfhi(v1.x) + bfhi(v2.x) + bfhi(v3.x);
            a2 += bflo(v0.y) + bflo(v1.y) + bflo(v2.y) + bflo(v3.y);
            a3 += bfhi(v0.y) + bfhi(v1.y) + bfhi(v2.y) + bfhi(v3.y);
            a4 += bflo(v0.z) + bflo(v1.z) + bflo(v2.z) + bflo(v3.z);
            a5 += bfhi(v0.z) + bfhi(v1.z) + bfhi(v2.z) + bfhi(v3.z);
            a6 += bflo(v0.w) + bflo(v1.w) + bflo(v2.w) + bflo(v3.w);
            a7 += bfhi(v0.w) + bfhi(v1.w) + bfhi(v2.w) + bfhi(v3.w);
        }
        for (; e < end; e++) {
            int s0 = esrc[e];
            uint4 v0 = *(const uint4*)(hsrc + (size_t)s0 * HIDF + l * 8);
            a0 += bflo(v0.x); a1 += bfhi(v0.x);
            a2 += bflo(v0.y); a3 += bfhi(v0.y);
            a4 += bflo(v0.z); a5 += bfhi(v0.z);
            a6 += bflo(v0.w); a7 += bfhi(v0.w);
        }
        uint4 o;
        o.x = (unsigned int)f2bf(a0 * w) | ((unsigned int)f2bf(a1 * w) << 16);
        o.y = (unsigned int)f2bf(a2 * w) | ((unsigned int)f2bf(a3 * w) << 16);
        o.z = (unsigned int)f2bf(a4 * w) | ((unsigned int)f2bf(a5 * w) << 16);
        o.w = (unsigned int)f2bf(a6 * w) | ((unsigned int)f2bf(a7 * w) << 16);
        // channels l*8.. -> kk = l>>2, chunk offset (l&3)*8 (16B aligned)
        *(uint4*)&A8[r][l >> 2][grp][(l & 3) * 8] = o;
    }

    // ---- phase 2: GEMM over K=1152 (9 slices of 128) ----
    floatx4 acc[2];
    acc[0] = (floatx4){0.f, 0.f, 0.f, 0.f};
    acc[1] = (floatx4){0.f, 0.f, 0.f, 0.f};

    for (int r = 0; r < RZ; r++) {
        // stage B slice r (verbatim transform9 pattern)
#pragma unroll
        for (int kk = 0; kk < 4; kk++)
#pragma unroll
            for (int p = 0; p < 2; p++) {
                int rr = (wave * 2 + p) * 16;
                gload_lds16(wz + ((size_t)r * 128 + rr + srow) * 128 + kk * 32 + sch * 8,
                            &B4[kk][rr][0]);
            }
        __syncthreads();   // first iter also fences phase-1 LDS writes

#pragma unroll
        for (int kk = 0; kk < 4; kk++) {
            short8 af, bfr[2];
            if (r < 8)
                af = *(const short8*)(&A8[r][kk][lq][quad * 8]);
            else  // root slice: A row = hsrc[n0+lq], k-chunk kk*32+quad*8 (L2-hot)
                af = *(const short8*)(hsrc + (size_t)(n0 + lq) * HIDF + kk * 32 + quad * 8);
#pragma unroll
            for (int j = 0; j < 2; j++)
                bfr[j] = *(const short8*)(&B4[kk][wave * 32 + j * 16 + lq][quad * 8]);
#pragma unroll
            for (int j = 0; j < 2; j++)
                acc[j] = __builtin_amdgcn_mfma_f32_16x16x32_bf16(af, bfr[j], acc[j], 0, 0, 0);
        }
        __syncthreads();
    }

    // epilogue: bias + relu + bf16 (C/D layout: col=lane&15, row=quad*4+reg)
#pragma unroll
    for (int j = 0; j < 2; j++) {
        int col = wave * 32 + j * 16 + lq;
        float bv = bias[col];
#pragma unroll
        for (int rg = 0; rg < 4; rg++) {
            int row = n0 + quad * 4 + rg;
            hout[(size_t)row * HIDF + col] = f2bf(fmaxf(acc[j][rg] + bv, 0.f));
        }
    }
}

// ---------------- global mean pool, two-stage, no atomics ----------------
__global__ __launch_bounds__(256) void pool1_kernel(const unsigned short* __restrict__ h,
                                                    const int* __restrict__ batch,
                                                    float* __restrict__ partial) {  // [G][PCHUNK][128]
    int g = blockIdx.x;
    int p = blockIdx.y;
    int lo, hi;
    {
        int l = 0, r = N_NODES;
        while (l < r) { int m = (l + r) >> 1; if (batch[m] < g) l = m + 1; else r = m; }
        lo = l;
        l = lo; r = N_NODES;
        while (l < r) { int m = (l + r) >> 1; if (batch[m] < g + 1) l = m + 1; else r = m; }
        hi = l;
    }
    int t = threadIdx.x;
    int rowlane = t >> 5;
    int c4 = t & 31;
    float a0 = 0.f, a1 = 0.f, a2 = 0.f, a3 = 0.f;
    for (int n = lo + p + rowlane * PCHUNK; n < hi; n += 8 * PCHUNK) {
        uint2 v = *(const uint2*)(h + (size_t)n * HIDF + c4 * 4);
        a0 += bflo(v.x); a1 += bfhi(v.x); a2 += bflo(v.y); a3 += bfhi(v.y);
    }
    __shared__ float red[8][128];
    if (rowlane == 0) {
        red[0][c4 * 4 + 0] = a0; red[0][c4 * 4 + 1] = a1;
        red[0][c4 * 4 + 2] = a2; red[0][c4 * 4 + 3] = a3;
    }
    __syncthreads();
    for (int s = 1; s < 8; s++) {
        if (rowlane == s) {
            red[0][c4 * 4 + 0] += a0; red[0][c4 * 4 + 1] += a1;
            red[0][c4 * 4 + 2] += a2; red[0][c4 * 4 + 3] += a3;
        }
        __syncthreads();
    }
    if (t < 128) partial[((size_t)g * PCHUNK + p) * 128 + t] = red[0][t];
}

// fused pool stage-2 + final linear: one block per graph
__global__ __launch_bounds__(128) void poolfin_kernel(const float* __restrict__ partial,
                                                      const int* __restrict__ batch,
                                                      const float* __restrict__ lin_w,  // [128,10]
                                                      const float* __restrict__ lin_b,  // [10]
                                                      float* __restrict__ out) {        // [64,10]
    __shared__ float gl[HIDF];
    int g = blockIdx.x;
    int lo, hi;
    {
        int l = 0, r = N_NODES;
        while (l < r) { int m = (l + r) >> 1; if (batch[m] < g) l = m + 1; else r = m; }
        lo = l;
        l = lo; r = N_NODES;
        while (l < r) { int m = (l + r) >> 1; if (batch[m] < g + 1) l = m + 1; else r = m; }
        hi = l;
    }
    int t = threadIdx.x;
    float s = 0.f;
#pragma unroll
    for (int p = 0; p < PCHUNK; p++)
        s += partial[((size_t)g * PCHUNK + p) * 128 + t];
    gl[t] = s / (float)max(hi - lo, 1);
    __syncthreads();
    if (t < CLSF) {
        float acc = lin_b[t];
#pragma unroll 16
        for (int d = 0; d < HIDF; d++) acc += gl[d] * lin_w[d * CLSF + t];
        out[g * CLSF + t] = acc;
    }
}

extern "C" void kernel_launch(void* const* d_in, const int* in_sizes, int n_in,
                              void* d_out, int out_size, void* d_ws, size_t ws_size,
                              hipStream_t stream) {
    const float* x     = (const float*)d_in[0];
    const int*   ei    = (const int*)d_in[1];
    const int*   et    = (const int*)d_in[2];
    const int*   batch = (const int*)d_in[3];
    const float* W1    = (const float*)d_in[4];
    const float* root1 = (const float*)d_in[5];
    const float* b1    = (const float*)d_in[6];
    const float* W2    = (const float*)d_in[7];
    const float* root2 = (const float*)d_in[8];
    const float* b2    = (const float*)d_in[9];
    const float* lin_w = (const float*)d_in[10];
    const float* lin_b = (const float*)d_in[11];
    float* out = (float*)d_out;

    const int* src = ei;            // edge_index[0]
    const int* dst = ei + N_EDGES;  // edge_index[1]

    char* ws = (char*)d_ws;
    unsigned short* xb  = (unsigned short*)ws; ws += (size_t)N_NODES * HIDF * 2;   // 12.8 MB
    unsigned short* h1  = (unsigned short*)ws; ws += (size_t)N_NODES * HIDF * 2;   // 12.8 MB
    unsigned short* h2  = (unsigned short*)ws; ws += (size_t)N_NODES * HIDF * 2;   // 12.8 MB
    unsigned short* wz1 = (unsigned short*)ws; ws += (size_t)RZ * 128 * 128 * 2;   // 288 KB
    unsigned short* wz2 = (unsigned short*)ws; ws += (size_t)RZ * 128 * 128 * 2;
    int*   seg    = (int*)ws;   ws += (size_t)N_EDGES * 4;                          // 6.4 MB
    int*   cnt    = (int*)ws;   ws += (size_t)S_SEG * 4;
    int*   off    = (int*)ws;   ws += (size_t)S_SEG * 4;
    int*   bsum   = (int*)ws;   ws += 512 * 4;
    int*   cursor = (int*)ws;   ws += (size_t)S_SEG * 4;
    unsigned short* esrc = (unsigned short*)ws; ws += (size_t)N_EDGES * 2;          // 3.2 MB
    float* partial = (float*)ws; ws += (size_t)G_GRAPHS * PCHUNK * 128 * 4;

    hipMemsetAsync(cnt, 0, (size_t)S_SEG * 4, stream);

    // ---- counting sort of edges by (dst, rel) segment (XCD-partitioned) ----
    seg_kernel<<<(N_EDGES / 4 + 255) / 256, 256, 0, stream>>>(dst, et, seg);
    count_kernel<<<SORT_GRID, 256, 0, stream>>>(seg, cnt);
    scan1_kernel<<<NB_SCAN, SCAN_BLK, 0, stream>>>(cnt, off, bsum);
    absoff2_kernel<<<NB_SCAN, 512, 0, stream>>>(off, bsum, cursor);
    bin_kernel<<<SORT_GRID, 256, 0, stream>>>(seg, src, cursor, esrc);

    // ---- bf16 conversions ----
    convx_kernel<<<(N_NODES * D_INF + 255) / 256, 256, 0, stream>>>(x, xb);
    convw9_kernel<<<dim3(8, 8, RZ), 256, 0, stream>>>(W1, root1, wz1);
    convw9_kernel<<<dim3(8, 8, RZ), 256, 0, stream>>>(W2, root2, wz2);

    const int NFB = N_NODES / 16;   // 3125 blocks, no tail

    // ---- fused layers: gather-mean in LDS + K=1152 MFMA (no m round-trip) ----
    fused_layer<<<NFB, 256, 0, stream>>>(xb, esrc, off, wz1, b1, h1);
    fused_layer<<<NFB, 256, 0, stream>>>(h1, esrc, off, wz2, b2, h2);

    // ---- pool (two-stage, no atomics) + classify ----
    pool1_kernel<<<dim3(G_GRAPHS, PCHUNK), 256, 0, stream>>>(h2, batch, partial);
    poolfin_kernel<<<G_GRAPHS, 128, 0, stream>>>(partial, batch, lin_w, lin_b, out);

    (void)in_sizes; (void)n_in; (void)out_size; (void)ws_size;
}

// Round 7
// 464.538 us; speedup vs baseline: 1.4609x; 1.4609x over previous
//
#include <hip/hip_runtime.h>

#define N_NODES 50000
#define N_EDGES 1600000
#define R_REL 8
#define G_GRAPHS 64
#define D_INF 128
#define HIDF 128
#define CLSF 10

#define S_SEG (N_NODES * R_REL)   // 400000 (dst, rel) segments
#define RZ 9                      // 8 relations + root slice
#define PCHUNK 16                 // pool stage-1 chunks per graph

#define XG 8                      // XCD groups for partitioned sort
#define NODES_PER_G (N_NODES / XG)      // 6250
#define SORT_BLKS_PER_G 256
#define SORT_GRID (XG * SORT_BLKS_PER_G)

typedef __attribute__((ext_vector_type(8))) short short8;
typedef __attribute__((ext_vector_type(4))) float floatx4;
typedef __attribute__((ext_vector_type(2))) float f32x2;

typedef __attribute__((address_space(1))) const unsigned int guint;
typedef __attribute__((address_space(3))) unsigned int luint;
__device__ __forceinline__ void gload_lds16(const void* g, void* l) {
    // async global->LDS, 16 B/lane; LDS dest = wave-uniform base + lane*16
    __builtin_amdgcn_global_load_lds((guint*)g, (luint*)l, 16, 0, 0);
}

__device__ __forceinline__ unsigned short f2bf(float f) {
    unsigned int u = __float_as_uint(f);
    unsigned int r = (u + 0x7fffu + ((u >> 16) & 1u)) >> 16;   // RNE
    return (unsigned short)r;
}
// exact unpack of a packed bf16 pair (uint32) into two fp32
__device__ __forceinline__ float bflo(unsigned int u) { return __uint_as_float(u << 16); }
__device__ __forceinline__ float bfhi(unsigned int u) { return __uint_as_float(u & 0xffff0000u); }
// packed pair (lo,hi) -> f32x2 for v_pk_add_f32 accumulation
__device__ __forceinline__ f32x2 bfpair(unsigned int u) {
    return (f32x2){__uint_as_float(u << 16), __uint_as_float(u & 0xffff0000u)};
}

__device__ __forceinline__ int ntload(const int* p) { return __builtin_nontemporal_load(p); }

// ---------------- pack (dst, rel) -> segment id, one vectorized pass ---------
__global__ __launch_bounds__(256) void seg_kernel(const int* __restrict__ dst,
                                                  const int* __restrict__ et,
                                                  int* __restrict__ seg) {
    int i4 = blockIdx.x * 256 + threadIdx.x;
    if (i4 * 4 >= N_EDGES) return;
    int4 d = ((const int4*)dst)[i4];
    int4 t = ((const int4*)et)[i4];
    int4 s;
    s.x = d.x * R_REL + t.x; s.y = d.y * R_REL + t.y;
    s.z = d.z * R_REL + t.z; s.w = d.w * R_REL + t.w;
    ((int4*)seg)[i4] = s;
}

// ---------------- count edges per (dst, rel) segment — XCD-partitioned --------
// 8 filter passes: all atomics land in one XCD's L2 (no cross-XCD line ping-pong).
__global__ __launch_bounds__(256) void count_kernel(const int* __restrict__ seg,
                                                    int* __restrict__ cnt) {
    int xg = blockIdx.x & (XG - 1);
    int inner = blockIdx.x >> 3;
    int lo = xg * NODES_PER_G * R_REL, hi = lo + NODES_PER_G * R_REL;
    for (int e = inner * 256 + threadIdx.x; e < N_EDGES; e += SORT_BLKS_PER_G * 256) {
        int sg = ntload(seg + e);
        if (sg >= lo && sg < hi) atomicAdd(&cnt[sg], 1);
    }
}

// ---------------- scan over segment counts ----------------
#define SCAN_BLK 256
#define SCAN_ELEMS 1024
#define NB_SCAN ((S_SEG + SCAN_ELEMS - 1) / SCAN_ELEMS)   // 391

__global__ __launch_bounds__(SCAN_BLK) void scan1_kernel(const int* __restrict__ cnt,
                                                         int* __restrict__ off,
                                                         int* __restrict__ bsum) {
    __shared__ int sd[SCAN_BLK];
    int t = threadIdx.x;
    int base = blockIdx.x * SCAN_ELEMS + t * 4;
    int v[4];
    int tsum = 0;
#pragma unroll
    for (int j = 0; j < 4; j++) {
        v[j] = (base + j < S_SEG) ? cnt[base + j] : 0;
        tsum += v[j];
    }
    sd[t] = tsum;
    __syncthreads();
    for (int d = 1; d < SCAN_BLK; d <<= 1) {
        int x = (t >= d) ? sd[t - d] : 0;
        __syncthreads();
        sd[t] += x;
        __syncthreads();
    }
    int incl = sd[t];
    int run = incl - tsum;
#pragma unroll
    for (int j = 0; j < 4; j++) {
        if (base + j < S_SEG) off[base + j] = run;
        run += v[j];
    }
    if (t == SCAN_BLK - 1) bsum[blockIdx.x] = incl;
}

// fused: scan of block sums (redundant per block, 391 values in LDS)
// + absolute off + cursor init. Replaces scan2 + absoff + memcpy(cursor).
__global__ __launch_bounds__(512) void absoff2_kernel(int* __restrict__ off,
                                                      const int* __restrict__ bsum,
                                                      int* __restrict__ cursor) {
    __shared__ int sd[512];
    int t = threadIdx.x;
    int v = (t < NB_SCAN) ? bsum[t] : 0;
    sd[t] = v;
    __syncthreads();
    for (int d = 1; d < 512; d <<= 1) {
        int x = (t >= d) ? sd[t - d] : 0;
        __syncthreads();
        sd[t] += x;
        __syncthreads();
    }
    int pre = (blockIdx.x == 0) ? 0 : sd[blockIdx.x - 1];
    int base = blockIdx.x * SCAN_ELEMS + t * 2;
#pragma unroll
    for (int j = 0; j < 2; j++) {
        int i = base + j;
        if (i < S_SEG) {
            int o = off[i] + pre;
            off[i] = o;
            cursor[i] = o;
        }
    }
}

// ---------------- bin edges — XCD-partitioned; 2B src record -----------------
// src load hoisted above the atomic: L2 atomic RT and src read overlap.
__global__ __launch_bounds__(256) void bin_kernel(const int* __restrict__ seg,
                                                  const int* __restrict__ src,
                                                  int* __restrict__ cursor,
                                                  unsigned short* __restrict__ esrc) {
    int xg = blockIdx.x & (XG - 1);
    int inner = blockIdx.x >> 3;
    int lo = xg * NODES_PER_G * R_REL, hi = lo + NODES_PER_G * R_REL;
    for (int e = inner * 256 + threadIdx.x; e < N_EDGES; e += SORT_BLKS_PER_G * 256) {
        int sg = ntload(seg + e);
        if (sg >= lo && sg < hi) {
            unsigned short s = (unsigned short)ntload(src + e);
            int pos = atomicAdd(&cursor[sg], 1);    // absolute position
            esrc[pos] = s;
        }
    }
}

// ---------------- convert x fp32 -> bf16 compact [N,128] ----------------
__global__ void convx_kernel(const float* __restrict__ x, unsigned short* __restrict__ xb) {
    int idx = blockIdx.x * blockDim.x + threadIdx.x;
    if (idx < N_NODES * D_INF) xb[idx] = f2bf(x[idx]);
}

// ---------------- build bf16 weights wz[9][128][128]: [r][col][k] ----------
__global__ __launch_bounds__(256) void convw9_kernel(const float* __restrict__ W,
                                                     const float* __restrict__ root,
                                                     unsigned short* __restrict__ wz) {
    __shared__ float t[16][17];
    int r = blockIdx.z;
    int k0 = blockIdx.x * 16, c0 = blockIdx.y * 16;
    int tx = threadIdx.x & 15, ty = threadIdx.x >> 4;
    const float* srcp = (r < 8) ? (W + (size_t)r * 128 * 128) : root;
    t[ty][tx] = srcp[(size_t)(k0 + ty) * 128 + c0 + tx];
    __syncthreads();
    wz[(size_t)r * 16384 + (size_t)(c0 + ty) * 128 + k0 + tx] = f2bf(t[tx][ty]);
}

// ---------------- segment mean: one 16-lane group per (dst,rel) segment ------
// w = 1/max(end-beg,1) from off[] directly. f32x2 accumulators -> v_pk_add_f32.
__global__ __launch_bounds__(256) void agg_mean(
    const unsigned short* __restrict__ hsrc,   // [N,128] bf16
    const unsigned short* __restrict__ esrc,   // src sorted by (dst,rel), 2B
    const int* __restrict__ off,               // [S_SEG] absolute starts
    unsigned short* __restrict__ m)            // [S_SEG][128] == [N][8][128]
{
    int sg = blockIdx.x * 16 + (threadIdx.x >> 4);
    int l = threadIdx.x & 15;                  // 16 lanes x 16B cover one 256B row
    int beg = off[sg];
    int end = (sg + 1 < S_SEG) ? off[sg + 1] : N_EDGES;
    float w = 1.0f / (float)max(end - beg, 1);

    f32x2 p0 = (f32x2){0.f, 0.f}, p1 = (f32x2){0.f, 0.f};
    f32x2 p2 = (f32x2){0.f, 0.f}, p3 = (f32x2){0.f, 0.f};
    int e = beg;
    for (; e + 4 <= end; e += 4) {
        int s0 = esrc[e], s1 = esrc[e + 1], s2 = esrc[e + 2], s3 = esrc[e + 3];
        uint4 v0 = *(const uint4*)(hsrc + (size_t)s0 * HIDF + l * 8);
        uint4 v1 = *(const uint4*)(hsrc + (size_t)s1 * HIDF + l * 8);
        uint4 v2 = *(const uint4*)(hsrc + (size_t)s2 * HIDF + l * 8);
        uint4 v3 = *(const uint4*)(hsrc + (size_t)s3 * HIDF + l * 8);
        p0 += bfpair(v0.x) + bfpair(v1.x) + bfpair(v2.x) + bfpair(v3.x);
        p1 += bfpair(v0.y) + bfpair(v1.y) + bfpair(v2.y) + bfpair(v3.y);
        p2 += bfpair(v0.z) + bfpair(v1.z) + bfpair(v2.z) + bfpair(v3.z);
        p3 += bfpair(v0.w) + bfpair(v1.w) + bfpair(v2.w) + bfpair(v3.w);
    }
    for (; e < end; e++) {
        int s0 = esrc[e];
        uint4 v0 = *(const uint4*)(hsrc + (size_t)s0 * HIDF + l * 8);
        p0 += bfpair(v0.x); p1 += bfpair(v0.y);
        p2 += bfpair(v0.z); p3 += bfpair(v0.w);
    }
    uint4 o;
    o.x = (unsigned int)f2bf(p0.x * w) | ((unsigned int)f2bf(p0.y * w) << 16);
    o.y = (unsigned int)f2bf(p1.x * w) | ((unsigned int)f2bf(p1.y * w) << 16);
    o.z = (unsigned int)f2bf(p2.x * w) | ((unsigned int)f2bf(p2.y * w) << 16);
    o.w = (unsigned int)f2bf(p3.x * w) | ((unsigned int)f2bf(p3.y * w) << 16);
    *(uint4*)(m + (size_t)sg * HIDF + l * 8) = o;
}

// ---------------- transform GEMM over K=1152: h = relu([m | hsrc] @ wz + b) ---
__global__ __launch_bounds__(256) void transform9(
    const unsigned short* __restrict__ mm,     // [N][8][128] bf16
    const unsigned short* __restrict__ hsrc,   // [N][128] bf16 (root operand)
    const unsigned short* __restrict__ wz,     // [9][128][128] bf16 [r][col][k]
    const float* __restrict__ bias,
    unsigned short* __restrict__ hout)         // [N][128] bf16
{
    __shared__ __align__(16) unsigned short A4[4][128][32];  // 32 KB
    __shared__ __align__(16) unsigned short B4[4][128][32];  // 32 KB

    const int tx = threadIdx.x;
    const int wave = tx >> 6, lane = tx & 63;
    const int quad = lane >> 4, lq = lane & 15;
    const int srow = lane >> 2, sch = lane & 3;
    const int row0 = blockIdx.x * 128;

    floatx4 acc[2][8];
#pragma unroll
    for (int i = 0; i < 2; i++)
#pragma unroll
        for (int j = 0; j < 8; j++) acc[i][j] = (floatx4){0.f, 0.f, 0.f, 0.f};

    for (int r = 0; r < RZ; r++) {
#pragma unroll
        for (int kk = 0; kk < 4; kk++) {
#pragma unroll
            for (int p = 0; p < 2; p++) {
                int rr = (wave * 2 + p) * 16;
                int gr = row0 + rr + srow; if (gr >= N_NODES) gr = N_NODES - 1;
                const unsigned short* ap = (r < 8)
                    ? mm + (size_t)gr * (R_REL * HIDF) + r * HIDF
                    : hsrc + (size_t)gr * HIDF;
                gload_lds16(ap + kk * 32 + sch * 8, &A4[kk][rr][0]);
                gload_lds16(wz + ((size_t)r * 128 + rr + srow) * 128 + kk * 32 + sch * 8,
                            &B4[kk][rr][0]);
            }
        }
        __syncthreads();

#pragma unroll
        for (int kk = 0; kk < 4; kk++) {
            short8 af[2], bfr[8];
#pragma unroll
            for (int i = 0; i < 2; i++)
                af[i] = *(const short8*)(&A4[kk][wave * 32 + i * 16 + lq][quad * 8]);
#pragma unroll
            for (int j = 0; j < 8; j++)
                bfr[j] = *(const short8*)(&B4[kk][j * 16 + lq][quad * 8]);
#pragma unroll
            for (int i = 0; i < 2; i++)
#pragma unroll
                for (int j = 0; j < 8; j++)
                    acc[i][j] = __builtin_amdgcn_mfma_f32_16x16x32_bf16(af[i], bfr[j], acc[i][j], 0, 0, 0);
        }
        __syncthreads();
    }

    // epilogue: bias + relu + bf16 pack (C/D layout col=lane&15, row=quad*4+reg)
#pragma unroll
    for (int i = 0; i < 2; i++)
#pragma unroll
        for (int j = 0; j < 8; j++) {
            int col = j * 16 + lq;
            float bv = bias[col];
#pragma unroll
            for (int rg = 0; rg < 4; rg++) {
                int row = row0 + wave * 32 + i * 16 + quad * 4 + rg;
                if (row < N_NODES)
                    hout[(size_t)row * HIDF + col] = f2bf(fmaxf(acc[i][j][rg] + bv, 0.f));
            }
        }
}

// ---------------- global mean pool, two-stage, no atomics ----------------
__global__ __launch_bounds__(256) void pool1_kernel(const unsigned short* __restrict__ h,
                                                    const int* __restrict__ batch,
                                                    float* __restrict__ partial) {  // [G][PCHUNK][128]
    int g = blockIdx.x;
    int p = blockIdx.y;
    int lo, hi;
    {
        int l = 0, r = N_NODES;
        while (l < r) { int m = (l + r) >> 1; if (batch[m] < g) l = m + 1; else r = m; }
        lo = l;
        l = lo; r = N_NODES;
        while (l < r) { int m = (l + r) >> 1; if (batch[m] < g + 1) l = m + 1; else r = m; }
        hi = l;
    }
    int t = threadIdx.x;
    int rowlane = t >> 5;
    int c4 = t & 31;
    float a0 = 0.f, a1 = 0.f, a2 = 0.f, a3 = 0.f;
    for (int n = lo + p + rowlane * PCHUNK; n < hi; n += 8 * PCHUNK) {
        uint2 v = *(const uint2*)(h + (size_t)n * HIDF + c4 * 4);
        a0 += bflo(v.x); a1 += bfhi(v.x); a2 += bflo(v.y); a3 += bfhi(v.y);
    }
    __shared__ float red[8][128];
    if (rowlane == 0) {
        red[0][c4 * 4 + 0] = a0; red[0][c4 * 4 + 1] = a1;
        red[0][c4 * 4 + 2] = a2; red[0][c4 * 4 + 3] = a3;
    }
    __syncthreads();
    for (int s = 1; s < 8; s++) {
        if (rowlane == s) {
            red[0][c4 * 4 + 0] += a0; red[0][c4 * 4 + 1] += a1;
            red[0][c4 * 4 + 2] += a2; red[0][c4 * 4 + 3] += a3;
        }
        __syncthreads();
    }
    if (t < 128) partial[((size_t)g * PCHUNK + p) * 128 + t] = red[0][t];
}

// fused pool stage-2 + final linear: one block per graph
__global__ __launch_bounds__(128) void poolfin_kernel(const float* __restrict__ partial,
                                                      const int* __restrict__ batch,
                                                      const float* __restrict__ lin_w,  // [128,10]
                                                      const float* __restrict__ lin_b,  // [10]
                                                      float* __restrict__ out) {        // [64,10]
    __shared__ float gl[HIDF];
    int g = blockIdx.x;
    int lo, hi;
    {
        int l = 0, r = N_NODES;
        while (l < r) { int m = (l + r) >> 1; if (batch[m] < g) l = m + 1; else r = m; }
        lo = l;
        l = lo; r = N_NODES;
        while (l < r) { int m = (l + r) >> 1; if (batch[m] < g + 1) l = m + 1; else r = m; }
        hi = l;
    }
    int t = threadIdx.x;
    float s = 0.f;
#pragma unroll
    for (int p = 0; p < PCHUNK; p++)
        s += partial[((size_t)g * PCHUNK + p) * 128 + t];
    gl[t] = s / (float)max(hi - lo, 1);
    __syncthreads();
    if (t < CLSF) {
        float acc = lin_b[t];
#pragma unroll 16
        for (int d = 0; d < HIDF; d++) acc += gl[d] * lin_w[d * CLSF + t];
        out[g * CLSF + t] = acc;
    }
}

extern "C" void kernel_launch(void* const* d_in, const int* in_sizes, int n_in,
                              void* d_out, int out_size, void* d_ws, size_t ws_size,
                              hipStream_t stream) {
    const float* x     = (const float*)d_in[0];
    const int*   ei    = (const int*)d_in[1];
    const int*   et    = (const int*)d_in[2];
    const int*   batch = (const int*)d_in[3];
    const float* W1    = (const float*)d_in[4];
    const float* root1 = (const float*)d_in[5];
    const float* b1    = (const float*)d_in[6];
    const float* W2    = (const float*)d_in[7];
    const float* root2 = (const float*)d_in[8];
    const float* b2    = (const float*)d_in[9];
    const float* lin_w = (const float*)d_in[10];
    const float* lin_b = (const float*)d_in[11];
    float* out = (float*)d_out;

    const int* src = ei;            // edge_index[0]
    const int* dst = ei + N_EDGES;  // edge_index[1]

    char* ws = (char*)d_ws;
    unsigned short* xb  = (unsigned short*)ws; ws += (size_t)N_NODES * HIDF * 2;   // 12.8 MB
    unsigned short* h1  = (unsigned short*)ws; ws += (size_t)N_NODES * HIDF * 2;   // 12.8 MB
    unsigned short* h2  = (unsigned short*)ws; ws += (size_t)N_NODES * HIDF * 2;   // 12.8 MB
    unsigned short* m   = (unsigned short*)ws; ws += (size_t)S_SEG * HIDF * 2;     // 102.4 MB
    unsigned short* wz1 = (unsigned short*)ws; ws += (size_t)RZ * 128 * 128 * 2;   // 288 KB
    unsigned short* wz2 = (unsigned short*)ws; ws += (size_t)RZ * 128 * 128 * 2;
    int*   seg    = (int*)ws;   ws += (size_t)N_EDGES * 4;                          // 6.4 MB
    int*   cnt    = (int*)ws;   ws += (size_t)S_SEG * 4;
    int*   off    = (int*)ws;   ws += (size_t)S_SEG * 4;
    int*   bsum   = (int*)ws;   ws += 512 * 4;
    int*   cursor = (int*)ws;   ws += (size_t)S_SEG * 4;
    unsigned short* esrc = (unsigned short*)ws; ws += (size_t)N_EDGES * 2;          // 3.2 MB
    float* partial = (float*)ws; ws += (size_t)G_GRAPHS * PCHUNK * 128 * 4;

    hipMemsetAsync(cnt, 0, (size_t)S_SEG * 4, stream);

    // ---- counting sort of edges by (dst, rel) segment (XCD-partitioned) ----
    seg_kernel<<<(N_EDGES / 4 + 255) / 256, 256, 0, stream>>>(dst, et, seg);
    count_kernel<<<SORT_GRID, 256, 0, stream>>>(seg, cnt);
    scan1_kernel<<<NB_SCAN, SCAN_BLK, 0, stream>>>(cnt, off, bsum);
    absoff2_kernel<<<NB_SCAN, 512, 0, stream>>>(off, bsum, cursor);
    bin_kernel<<<SORT_GRID, 256, 0, stream>>>(seg, src, cursor, esrc);

    // ---- bf16 conversions ----
    convx_kernel<<<(N_NODES * D_INF + 255) / 256, 256, 0, stream>>>(x, xb);
    convw9_kernel<<<dim3(8, 8, RZ), 256, 0, stream>>>(W1, root1, wz1);
    convw9_kernel<<<dim3(8, 8, RZ), 256, 0, stream>>>(W2, root2, wz2);

    const int NGB = (N_NODES + 127) / 128;   // 391
    const int NSB = S_SEG / 16;              // 25000

    // ---- layer 1: aggregate-first (parallel), then K=1152 GEMM ----
    agg_mean<<<NSB, 256, 0, stream>>>(xb, esrc, off, m);
    transform9<<<NGB, 256, 0, stream>>>(m, xb, wz1, b1, h1);

    // ---- layer 2 ----
    agg_mean<<<NSB, 256, 0, stream>>>(h1, esrc, off, m);
    transform9<<<NGB, 256, 0, stream>>>(m, h1, wz2, b2, h2);

    // ---- pool (two-stage, no atomics) + classify ----
    pool1_kernel<<<dim3(G_GRAPHS, PCHUNK), 256, 0, stream>>>(h2, batch, partial);
    poolfin_kernel<<<G_GRAPHS, 128, 0, stream>>>(partial, batch, lin_w, lin_b, out);

    (void)in_sizes; (void)n_in; (void)out_size; (void)ws_size;
}

// Round 8
// 430.244 us; speedup vs baseline: 1.5774x; 1.0797x over previous
//
#include <hip/hip_runtime.h>

#define N_NODES 50000
#define N_EDGES 1600000
#define R_REL 8
#define G_GRAPHS 64
#define D_INF 128
#define HIDF 128
#define CLSF 10

#define S_SEG (N_NODES * R_REL)   // 400000 (dst, rel) segments
#define RZ 9                      // 8 relations + root slice
#define PCHUNK 16                 // pool stage-1 chunks per graph

#define XG 8                      // XCD groups for partitioned count
#define NODES_PER_G (N_NODES / XG)        // 6250
#define SEGS_PER_G (NODES_PER_G * R_REL)  // 50000
#define SORT_BLKS_PER_G 256
#define SORT_GRID (XG * SORT_BLKS_PER_G)

typedef __attribute__((ext_vector_type(8))) short short8;
typedef __attribute__((ext_vector_type(4))) float floatx4;
typedef __attribute__((ext_vector_type(2))) float f32x2;

typedef __attribute__((address_space(1))) const unsigned int guint;
typedef __attribute__((address_space(3))) unsigned int luint;
__device__ __forceinline__ void gload_lds16(const void* g, void* l) {
    // async global->LDS, 16 B/lane; LDS dest = wave-uniform base + lane*16
    __builtin_amdgcn_global_load_lds((guint*)g, (luint*)l, 16, 0, 0);
}

__device__ __forceinline__ unsigned short f2bf(float f) {
    unsigned int u = __float_as_uint(f);
    unsigned int r = (u + 0x7fffu + ((u >> 16) & 1u)) >> 16;   // RNE
    return (unsigned short)r;
}
// exact unpack of a packed bf16 pair (uint32) into two fp32
__device__ __forceinline__ float bflo(unsigned int u) { return __uint_as_float(u << 16); }
__device__ __forceinline__ float bfhi(unsigned int u) { return __uint_as_float(u & 0xffff0000u); }
// packed pair (lo,hi) -> f32x2 for v_pk_add_f32 accumulation
__device__ __forceinline__ f32x2 bfpair(unsigned int u) {
    return (f32x2){__uint_as_float(u << 16), __uint_as_float(u & 0xffff0000u)};
}

__device__ __forceinline__ int ntload(const int* p) { return __builtin_nontemporal_load(p); }

// ---------------- pack (dst, rel) -> segment id, one vectorized pass ---------
__global__ __launch_bounds__(256) void seg_kernel(const int* __restrict__ dst,
                                                  const int* __restrict__ et,
                                                  int* __restrict__ seg) {
    int i4 = blockIdx.x * 256 + threadIdx.x;
    if (i4 * 4 >= N_EDGES) return;
    int4 d = ((const int4*)dst)[i4];
    int4 t = ((const int4*)et)[i4];
    int4 s;
    s.x = d.x * R_REL + t.x; s.y = d.y * R_REL + t.y;
    s.z = d.z * R_REL + t.z; s.w = d.w * R_REL + t.w;
    ((int4*)seg)[i4] = s;
}

// ---------------- count + rank per (dst, rel) segment — XCD-partitioned -------
// 8 filter passes: XCD-local atomic targets. atomicAdd's return value IS the
// edge's stable rank within its segment -> no second atomic pass needed.
__global__ __launch_bounds__(256) void count_kernel(const int* __restrict__ seg,
                                                    int* __restrict__ cnt,
                                                    unsigned short* __restrict__ rank) {
    int xg = blockIdx.x & (XG - 1);
    int inner = blockIdx.x >> 3;
    int lo = xg * SEGS_PER_G, hi = lo + SEGS_PER_G;
    for (int e = inner * 256 + threadIdx.x; e < N_EDGES; e += SORT_BLKS_PER_G * 256) {
        int sg = ntload(seg + e);
        if (sg >= lo && sg < hi)
            rank[e] = (unsigned short)atomicAdd(&cnt[sg], 1);
    }
}

// ---------------- scan over segment counts ----------------
#define SCAN_BLK 256
#define SCAN_ELEMS 1024
#define NB_SCAN ((S_SEG + SCAN_ELEMS - 1) / SCAN_ELEMS)   // 391

__global__ __launch_bounds__(SCAN_BLK) void scan1_kernel(const int* __restrict__ cnt,
                                                         int* __restrict__ off,
                                                         int* __restrict__ bsum) {
    __shared__ int sd[SCAN_BLK];
    int t = threadIdx.x;
    int base = blockIdx.x * SCAN_ELEMS + t * 4;
    int v[4];
    int tsum = 0;
#pragma unroll
    for (int j = 0; j < 4; j++) {
        v[j] = (base + j < S_SEG) ? cnt[base + j] : 0;
        tsum += v[j];
    }
    sd[t] = tsum;
    __syncthreads();
    for (int d = 1; d < SCAN_BLK; d <<= 1) {
        int x = (t >= d) ? sd[t - d] : 0;
        __syncthreads();
        sd[t] += x;
        __syncthreads();
    }
    int incl = sd[t];
    int run = incl - tsum;
#pragma unroll
    for (int j = 0; j < 4; j++) {
        if (base + j < S_SEG) off[base + j] = run;
        run += v[j];
    }
    if (t == SCAN_BLK - 1) bsum[blockIdx.x] = incl;
}

// fused: redundant per-block scan of the 391 block sums + absolute off.
__global__ __launch_bounds__(512) void absoff2_kernel(int* __restrict__ off,
                                                      const int* __restrict__ bsum) {
    __shared__ int sd[512];
    int t = threadIdx.x;
    int v = (t < NB_SCAN) ? bsum[t] : 0;
    sd[t] = v;
    __syncthreads();
    for (int d = 1; d < 512; d <<= 1) {
        int x = (t >= d) ? sd[t - d] : 0;
        __syncthreads();
        sd[t] += x;
        __syncthreads();
    }
    int pre = (blockIdx.x == 0) ? 0 : sd[blockIdx.x - 1];
    int base = blockIdx.x * SCAN_ELEMS + t * 2;
#pragma unroll
    for (int j = 0; j < 2; j++) {
        int i = base + j;
        if (i < S_SEG) off[i] += pre;
    }
}

// ---------------- scatter: single pass, NO atomics (pos = off[sg] + rank) ----
__global__ __launch_bounds__(256) void scatter_kernel(const int* __restrict__ seg,
                                                      const int* __restrict__ src,
                                                      const unsigned short* __restrict__ rank,
                                                      const int* __restrict__ off,
                                                      unsigned short* __restrict__ esrc) {
    int i4 = blockIdx.x * 256 + threadIdx.x;
    if (i4 * 4 >= N_EDGES) return;
    int4 s4 = ((const int4*)seg)[i4];
    int4 r4 = ((const int4*)src)[i4];
    ushort4 k4 = ((const ushort4*)rank)[i4];
    esrc[off[s4.x] + k4.x] = (unsigned short)r4.x;
    esrc[off[s4.y] + k4.y] = (unsigned short)r4.y;
    esrc[off[s4.z] + k4.z] = (unsigned short)r4.z;
    esrc[off[s4.w] + k4.w] = (unsigned short)r4.w;
}

// ---------------- convert x fp32 -> bf16 compact [N,128] ----------------
__global__ void convx_kernel(const float* __restrict__ x, unsigned short* __restrict__ xb) {
    int idx = blockIdx.x * blockDim.x + threadIdx.x;
    if (idx < N_NODES * D_INF) xb[idx] = f2bf(x[idx]);
}

// ---------------- build bf16 weights wz[9][128][128]: [r][col][k] ----------
__global__ __launch_bounds__(256) void convw9_kernel(const float* __restrict__ W,
                                                     const float* __restrict__ root,
                                                     unsigned short* __restrict__ wz) {
    __shared__ float t[16][17];
    int r = blockIdx.z;
    int k0 = blockIdx.x * 16, c0 = blockIdx.y * 16;
    int tx = threadIdx.x & 15, ty = threadIdx.x >> 4;
    const float* srcp = (r < 8) ? (W + (size_t)r * 128 * 128) : root;
    t[ty][tx] = srcp[(size_t)(k0 + ty) * 128 + c0 + tx];
    __syncthreads();
    wz[(size_t)r * 16384 + (size_t)(c0 + ty) * 128 + k0 + tx] = f2bf(t[tx][ty]);
}

// ---------------- segment mean: one 16-lane group per (dst,rel) segment ------
__global__ __launch_bounds__(256) void agg_mean(
    const unsigned short* __restrict__ hsrc,   // [N,128] bf16
    const unsigned short* __restrict__ esrc,   // src sorted by (dst,rel), 2B
    const int* __restrict__ off,               // [S_SEG] absolute starts
    unsigned short* __restrict__ m)            // [S_SEG][128] == [N][8][128]
{
    int sg = blockIdx.x * 16 + (threadIdx.x >> 4);
    int l = threadIdx.x & 15;                  // 16 lanes x 16B cover one 256B row
    int beg = off[sg];
    int end = (sg + 1 < S_SEG) ? off[sg + 1] : N_EDGES;
    float w = 1.0f / (float)max(end - beg, 1);

    f32x2 p0 = (f32x2){0.f, 0.f}, p1 = (f32x2){0.f, 0.f};
    f32x2 p2 = (f32x2){0.f, 0.f}, p3 = (f32x2){0.f, 0.f};
    int e = beg;
    for (; e + 4 <= end; e += 4) {
        int s0 = esrc[e], s1 = esrc[e + 1], s2 = esrc[e + 2], s3 = esrc[e + 3];
        uint4 v0 = *(const uint4*)(hsrc + (size_t)s0 * HIDF + l * 8);
        uint4 v1 = *(const uint4*)(hsrc + (size_t)s1 * HIDF + l * 8);
        uint4 v2 = *(const uint4*)(hsrc + (size_t)s2 * HIDF + l * 8);
        uint4 v3 = *(const uint4*)(hsrc + (size_t)s3 * HIDF + l * 8);
        p0 += bfpair(v0.x) + bfpair(v1.x) + bfpair(v2.x) + bfpair(v3.x);
        p1 += bfpair(v0.y) + bfpair(v1.y) + bfpair(v2.y) + bfpair(v3.y);
        p2 += bfpair(v0.z) + bfpair(v1.z) + bfpair(v2.z) + bfpair(v3.z);
        p3 += bfpair(v0.w) + bfpair(v1.w) + bfpair(v2.w) + bfpair(v3.w);
    }
    for (; e < end; e++) {
        int s0 = esrc[e];
        uint4 v0 = *(const uint4*)(hsrc + (size_t)s0 * HIDF + l * 8);
        p0 += bfpair(v0.x); p1 += bfpair(v0.y);
        p2 += bfpair(v0.z); p3 += bfpair(v0.w);
    }
    uint4 o;
    o.x = (unsigned int)f2bf(p0.x * w) | ((unsigned int)f2bf(p0.y * w) << 16);
    o.y = (unsigned int)f2bf(p1.x * w) | ((unsigned int)f2bf(p1.y * w) << 16);
    o.z = (unsigned int)f2bf(p2.x * w) | ((unsigned int)f2bf(p2.y * w) << 16);
    o.w = (unsigned int)f2bf(p3.x * w) | ((unsigned int)f2bf(p3.y * w) << 16);
    *(uint4*)(m + (size_t)sg * HIDF + l * 8) = o;
}

// ---------------- transform GEMM over K=1152: h = relu([m | hsrc] @ wz + b) ---
__global__ __launch_bounds__(256) void transform9(
    const unsigned short* __restrict__ mm,     // [N][8][128] bf16
    const unsigned short* __restrict__ hsrc,   // [N][128] bf16 (root operand)
    const unsigned short* __restrict__ wz,     // [9][128][128] bf16 [r][col][k]
    const float* __restrict__ bias,
    unsigned short* __restrict__ hout)         // [N][128] bf16
{
    __shared__ __align__(16) unsigned short A4[4][128][32];  // 32 KB
    __shared__ __align__(16) unsigned short B4[4][128][32];  // 32 KB

    const int tx = threadIdx.x;
    const int wave = tx >> 6, lane = tx & 63;
    const int quad = lane >> 4, lq = lane & 15;
    const int srow = lane >> 2, sch = lane & 3;
    const int row0 = blockIdx.x * 128;

    floatx4 acc[2][8];
#pragma unroll
    for (int i = 0; i < 2; i++)
#pragma unroll
        for (int j = 0; j < 8; j++) acc[i][j] = (floatx4){0.f, 0.f, 0.f, 0.f};

    for (int r = 0; r < RZ; r++) {
#pragma unroll
        for (int kk = 0; kk < 4; kk++) {
#pragma unroll
            for (int p = 0; p < 2; p++) {
                int rr = (wave * 2 + p) * 16;
                int gr = row0 + rr + srow; if (gr >= N_NODES) gr = N_NODES - 1;
                const unsigned short* ap = (r < 8)
                    ? mm + (size_t)gr * (R_REL * HIDF) + r * HIDF
                    : hsrc + (size_t)gr * HIDF;
                gload_lds16(ap + kk * 32 + sch * 8, &A4[kk][rr][0]);
                gload_lds16(wz + ((size_t)r * 128 + rr + srow) * 128 + kk * 32 + sch * 8,
                            &B4[kk][rr][0]);
            }
        }
        __syncthreads();

#pragma unroll
        for (int kk = 0; kk < 4; kk++) {
            short8 af[2], bfr[8];
#pragma unroll
            for (int i = 0; i < 2; i++)
                af[i] = *(const short8*)(&A4[kk][wave * 32 + i * 16 + lq][quad * 8]);
#pragma unroll
            for (int j = 0; j < 8; j++)
                bfr[j] = *(const short8*)(&B4[kk][j * 16 + lq][quad * 8]);
#pragma unroll
            for (int i = 0; i < 2; i++)
#pragma unroll
                for (int j = 0; j < 8; j++)
                    acc[i][j] = __builtin_amdgcn_mfma_f32_16x16x32_bf16(af[i], bfr[j], acc[i][j], 0, 0, 0);
        }
        __syncthreads();
    }

    // epilogue: bias + relu + bf16 pack (C/D layout col=lane&15, row=quad*4+reg)
#pragma unroll
    for (int i = 0; i < 2; i++)
#pragma unroll
        for (int j = 0; j < 8; j++) {
            int col = j * 16 + lq;
            float bv = bias[col];
#pragma unroll
            for (int rg = 0; rg < 4; rg++) {
                int row = row0 + wave * 32 + i * 16 + quad * 4 + rg;
                if (row < N_NODES)
                    hout[(size_t)row * HIDF + col] = f2bf(fmaxf(acc[i][j][rg] + bv, 0.f));
            }
        }
}

// ---------------- global mean pool, two-stage, no atomics ----------------
__global__ __launch_bounds__(256) void pool1_kernel(const unsigned short* __restrict__ h,
                                                    const int* __restrict__ batch,
                                                    float* __restrict__ partial) {  // [G][PCHUNK][128]
    int g = blockIdx.x;
    int p = blockIdx.y;
    int lo, hi;
    {
        int l = 0, r = N_NODES;
        while (l < r) { int m = (l + r) >> 1; if (batch[m] < g) l = m + 1; else r = m; }
        lo = l;
        l = lo; r = N_NODES;
        while (l < r) { int m = (l + r) >> 1; if (batch[m] < g + 1) l = m + 1; else r = m; }
        hi = l;
    }
    int t = threadIdx.x;
    int rowlane = t >> 5;
    int c4 = t & 31;
    float a0 = 0.f, a1 = 0.f, a2 = 0.f, a3 = 0.f;
    for (int n = lo + p + rowlane * PCHUNK; n < hi; n += 8 * PCHUNK) {
        uint2 v = *(const uint2*)(h + (size_t)n * HIDF + c4 * 4);
        a0 += bflo(v.x); a1 += bfhi(v.x); a2 += bflo(v.y); a3 += bfhi(v.y);
    }
    __shared__ float red[8][128];
    if (rowlane == 0) {
        red[0][c4 * 4 + 0] = a0; red[0][c4 * 4 + 1] = a1;
        red[0][c4 * 4 + 2] = a2; red[0][c4 * 4 + 3] = a3;
    }
    __syncthreads();
    for (int s = 1; s < 8; s++) {
        if (rowlane == s) {
            red[0][c4 * 4 + 0] += a0; red[0][c4 * 4 + 1] += a1;
            red[0][c4 * 4 + 2] += a2; red[0][c4 * 4 + 3] += a3;
        }
        __syncthreads();
    }
    if (t < 128) partial[((size_t)g * PCHUNK + p) * 128 + t] = red[0][t];
}

// fused pool stage-2 + final linear: one block per graph
__global__ __launch_bounds__(128) void poolfin_kernel(const float* __restrict__ partial,
                                                      const int* __restrict__ batch,
                                                      const float* __restrict__ lin_w,  // [128,10]
                                                      const float* __restrict__ lin_b,  // [10]
                                                      float* __restrict__ out) {        // [64,10]
    __shared__ float gl[HIDF];
    int g = blockIdx.x;
    int lo, hi;
    {
        int l = 0, r = N_NODES;
        while (l < r) { int m = (l + r) >> 1; if (batch[m] < g) l = m + 1; else r = m; }
        lo = l;
        l = lo; r = N_NODES;
        while (l < r) { int m = (l + r) >> 1; if (batch[m] < g + 1) l = m + 1; else r = m; }
        hi = l;
    }
    int t = threadIdx.x;
    float s = 0.f;
#pragma unroll
    for (int p = 0; p < PCHUNK; p++)
        s += partial[((size_t)g * PCHUNK + p) * 128 + t];
    gl[t] = s / (float)max(hi - lo, 1);
    __syncthreads();
    if (t < CLSF) {
        float acc = lin_b[t];
#pragma unroll 16
        for (int d = 0; d < HIDF; d++) acc += gl[d] * lin_w[d * CLSF + t];
        out[g * CLSF + t] = acc;
    }
}

extern "C" void kernel_launch(void* const* d_in, const int* in_sizes, int n_in,
                              void* d_out, int out_size, void* d_ws, size_t ws_size,
                              hipStream_t stream) {
    const float* x     = (const float*)d_in[0];
    const int*   ei    = (const int*)d_in[1];
    const int*   et    = (const int*)d_in[2];
    const int*   batch = (const int*)d_in[3];
    const float* W1    = (const float*)d_in[4];
    const float* root1 = (const float*)d_in[5];
    const float* b1    = (const float*)d_in[6];
    const float* W2    = (const float*)d_in[7];
    const float* root2 = (const float*)d_in[8];
    const float* b2    = (const float*)d_in[9];
    const float* lin_w = (const float*)d_in[10];
    const float* lin_b = (const float*)d_in[11];
    float* out = (float*)d_out;

    const int* src = ei;            // edge_index[0]
    const int* dst = ei + N_EDGES;  // edge_index[1]

    char* ws = (char*)d_ws;
    unsigned short* xb  = (unsigned short*)ws; ws += (size_t)N_NODES * HIDF * 2;   // 12.8 MB
    unsigned short* h1  = (unsigned short*)ws; ws += (size_t)N_NODES * HIDF * 2;   // 12.8 MB
    unsigned short* h2  = (unsigned short*)ws; ws += (size_t)N_NODES * HIDF * 2;   // 12.8 MB
    unsigned short* m   = (unsigned short*)ws; ws += (size_t)S_SEG * HIDF * 2;     // 102.4 MB
    unsigned short* wz1 = (unsigned short*)ws; ws += (size_t)RZ * 128 * 128 * 2;   // 288 KB
    unsigned short* wz2 = (unsigned short*)ws; ws += (size_t)RZ * 128 * 128 * 2;
    int*   seg    = (int*)ws;   ws += (size_t)N_EDGES * 4;                          // 6.4 MB
    int*   cnt    = (int*)ws;   ws += (size_t)S_SEG * 4;
    int*   off    = (int*)ws;   ws += (size_t)S_SEG * 4;
    int*   bsum   = (int*)ws;   ws += 512 * 4;
    unsigned short* rank = (unsigned short*)ws; ws += (size_t)N_EDGES * 2;          // 3.2 MB
    unsigned short* esrc = (unsigned short*)ws; ws += (size_t)N_EDGES * 2;          // 3.2 MB
    float* partial = (float*)ws; ws += (size_t)G_GRAPHS * PCHUNK * 128 * 4;

    hipMemsetAsync(cnt, 0, (size_t)S_SEG * 4, stream);

    // ---- counting sort: count(+rank) -> scan -> atomic-free scatter ----
    seg_kernel<<<(N_EDGES / 4 + 255) / 256, 256, 0, stream>>>(dst, et, seg);
    count_kernel<<<SORT_GRID, 256, 0, stream>>>(seg, cnt, rank);
    scan1_kernel<<<NB_SCAN, SCAN_BLK, 0, stream>>>(cnt, off, bsum);
    absoff2_kernel<<<NB_SCAN, 512, 0, stream>>>(off, bsum);
    scatter_kernel<<<(N_EDGES / 4 + 255) / 256, 256, 0, stream>>>(seg, src, rank, off, esrc);

    // ---- bf16 conversions ----
    convx_kernel<<<(N_NODES * D_INF + 255) / 256, 256, 0, stream>>>(x, xb);
    convw9_kernel<<<dim3(8, 8, RZ), 256, 0, stream>>>(W1, root1, wz1);
    convw9_kernel<<<dim3(8, 8, RZ), 256, 0, stream>>>(W2, root2, wz2);

    const int NGB = (N_NODES + 127) / 128;   // 391
    const int NSB = S_SEG / 16;              // 25000

    // ---- layer 1: aggregate-first (parallel), then K=1152 GEMM ----
    agg_mean<<<NSB, 256, 0, stream>>>(xb, esrc, off, m);
    transform9<<<NGB, 256, 0, stream>>>(m, xb, wz1, b1, h1);

    // ---- layer 2 ----
    agg_mean<<<NSB, 256, 0, stream>>>(h1, esrc, off, m);
    transform9<<<NGB, 256, 0, stream>>>(m, h1, wz2, b2, h2);

    // ---- pool (two-stage, no atomics) + classify ----
    pool1_kernel<<<dim3(G_GRAPHS, PCHUNK), 256, 0, stream>>>(h2, batch, partial);
    poolfin_kernel<<<G_GRAPHS, 128, 0, stream>>>(partial, batch, lin_w, lin_b, out);

    (void)in_sizes; (void)n_in; (void)out_size; (void)ws_size;
}